// Round 8
// baseline (94.569 us; speedup 1.0000x reference)
//
#include <hip/hip_runtime.h>
#include <hip/hip_bf16.h>

#define NATOMS 2048
#define K 48
#define NR 5
#define NM 12
#define ND 17
#define HID 64

#define PI_F 3.14159265358979f
#define CUT 3.0f
#define RMIN_F 3.5f
#define AFC (-6.28318530717959f)   /* pi/(CUT-RMIN) = pi/(-0.5) */
#define POC (PI_F / CUT)           /* pi/3 */
#define SQ 0.816496580927726f      /* sqrt(2/3) */
#define CMC (-0.132231404958678f)  /* -16/121 */
/* exp2-folded constants (x * log2(e)) */
#define N4L (-5.77078016355585f)   /* -4 * log2e */
#define E1L (2.09846551402031f)    /* (16/11) * log2e */
#define TL2 (2.88539008177793f)    /* 2 * log2e */

// Packed bf16 weight layouts (built once per launch by k_prep).
__device__ unsigned short g_w1t[64 * 32];  // [n=h][k=j]  (k>=17 zero)
__device__ unsigned short g_w2t[64 * 64];  // [n=h2][k=h1]
__device__ unsigned short g_w2r[64 * 64];  // [n=h1][k=h2]
__device__ unsigned short g_w1r[32 * 64];  // [n=j][k=h]  (n>=17 zero)

using frag_ab = __attribute__((ext_vector_type(8))) short;
using frag_cd = __attribute__((ext_vector_type(4))) float;
using f2 = __attribute__((ext_vector_type(2))) float;
using f4 = __attribute__((ext_vector_type(4))) float;
using s4 = __attribute__((ext_vector_type(4))) short;

__device__ __forceinline__ float fast_tanh(float x) {
    const float t = __builtin_amdgcn_exp2f(TL2 * x);
    return 1.0f - 2.0f * __builtin_amdgcn_rcpf(t + 1.0f);
}

__device__ __forceinline__ unsigned short f2bs(float x) {
    __hip_bfloat16 b = __float2bfloat16(x);
    return __builtin_bit_cast(unsigned short, b);
}

__device__ __forceinline__ float bs2f(unsigned short u) {
    return __builtin_bit_cast(float, ((unsigned)u) << 16);
}

// DPP cross-lane add; 0x110|s = row_shr s (16-lane sum lands in lane 15).
template <int CTRL>
__device__ __forceinline__ float dpp_add(float x) {
    const int y = __builtin_amdgcn_update_dpp(
        0, __builtin_bit_cast(int, x), CTRL, 0xF, 0xF, true);
    return x + __builtin_bit_cast(float, y);
}

// ---------------- Kernel 0: pack weights into MFMA-ready bf16 layouts -----
__global__ __launch_bounds__(256) void k_prep(const float* __restrict__ W1,
                                              const float* __restrict__ W2) {
    const int i = blockIdx.x * 256 + threadIdx.x;  // grid covers 12288
    if (i < 2048) {                                   // W1T[n][k]
        const int n = i >> 5, k = i & 31;
        g_w1t[i] = (k < ND) ? f2bs(W1[k * HID + n]) : (unsigned short)0;
    } else if (i < 2048 + 4096) {                     // W2T[n][k]
        const int j = i - 2048, n = j >> 6, k = j & 63;
        g_w2t[j] = f2bs(W2[k * HID + n]);
    } else if (i < 2048 + 8192) {                     // W2R[n][k]
        const int j = i - (2048 + 4096);
        g_w2r[j] = f2bs(W2[j]);
    } else if (i < 2048 + 8192 + 2048) {              // W1R[n][k]
        const int j = i - (2048 + 8192), n = j >> 6;
        g_w1r[j] = (n < ND) ? f2bs(W1[j]) : (unsigned short)0;
    }
}

// ---------------- Fused kernel: block = 1 WAVE = 1 atom. ZERO barriers. ---
// One wave does the entire atom in program order; within-wave LDS ordering
// is lgkmcnt-enforced; no cross-wave coupling of any kind. 8 blocks/CU
// resident (grid = exactly 8/CU), 2 independent waves/SIMD.
// S/T stored TRANSPOSED ([l][k]) so the column reductions become per-lane
// contiguous row reads (b64).
// LDS 18,816 B:
//  H1  @0     (6912): h1 then gz1, [48][72] bf16 | tT [48][52] @0 (4992)
//  GZ2 @6912  (6912): gz2 [48][72] bf16          | tS [48][52] @4992 (4992)
//  DESC@13824 (3840): desc [48][40] bf16 | sgd f32 [48][20] (overlay)
//  SU  @17664 (768), SFC @18432 (192), SFK @18624 (192)
#define H1_OFF   0
#define TT_OFF   0
#define SST_OFF  4992
#define GZ2_OFF  6912
#define DESC_OFF 13824
#define SGD_OFF  13824
#define SU_OFF   17664
#define SFC_OFF  18432
#define SFK_OFF  18624
#define SM_BYTES 18816

__global__ __launch_bounds__(64, 2) void k_fused(const float* __restrict__ rij,
                                                 const float* __restrict__ b1,
                                                 const float* __restrict__ b2,
                                                 const float* __restrict__ W3,
                                                 const float* __restrict__ b3,
                                                 float* __restrict__ out) {
    __shared__ __align__(16) char smem[SM_BYTES];
    short*          h1S   = (short*)(smem + H1_OFF);            // [row*72+n]
    unsigned short* tT    = (unsigned short*)(smem + TT_OFF);   // [l*52+k] bf16 (T^T)
    unsigned short* tS    = (unsigned short*)(smem + SST_OFF);  // [l*52+k] bf16 (S^T)
    short*          gz2S  = (short*)(smem + GZ2_OFF);           // [row*72+n]
    short*          descS = (short*)(smem + DESC_OFF);          // [row*40+j]
    float*          sgd   = (float*)(smem + SGD_OFF);           // [row*20+{0..16,17:eij}]
    float*          su    = (float*)(smem + SU_OFF);            // [4k+{x,y,z,d}]
    float*          sfc   = (float*)(smem + SFC_OFF);
    float*          sfk   = (float*)(smem + SFK_OFF);

    const int lane = threadIdx.x;            // 0..63, one wave
    const int quad = lane >> 4, lm = lane & 15;
    const int base3 = blockIdx.x * (K * 3);

    // per-column scalars for all 4 N-tiles (L2-broadcast)
    float b1v[4], b2v[4], w3v[4];
#pragma unroll
    for (int nt = 0; nt < 4; nt++) {
        b1v[nt] = b1[nt * 16 + lm];
        b2v[nt] = b2[nt * 16 + lm];
        w3v[nt] = W3[nt * 16 + lm];
    }
    const float b3v = b3[0];

    // ---- ph0: geometry + rbf (sin/cos recurrence) + K-pad ----
    if (lane < K) {
        const float x = rij[base3 + 3 * lane];
        const float y = rij[base3 + 3 * lane + 1];
        const float z = rij[base3 + 3 * lane + 2];
        float s2 = fmaxf(x * x + y * y + z * z, 1e-24f);
        const float inv = __builtin_amdgcn_rsqf(s2);
        const float d = s2 * inv;
        *(f4*)&su[4 * lane] = (f4){x * inv, y * inv, z * inv, d};
        sfk[lane] = 0.5f + 0.5f * __cosf(POC * d);
        const float fc = (d > RMIN_F) ? (0.5f + 0.5f * __cosf(AFC * (d - RMIN_F))) : 1.0f;
        sfc[lane] = fc;
        float s1, c1;
        __sincosf(POC * d, &s1, &c1);
        const float sc = SQ * fc * inv;
        float sn = s1, cn = c1;
#pragma unroll 1
        for (int n = 0; n < NR; n++) {
            descS[lane * 40 + n] = (short)f2bs(sc * sn);
            const float snx = sn * c1 + cn * s1;
            cn = cn * c1 - sn * s1;
            sn = snx;
        }
#pragma unroll 1
        for (int c = ND; c < 32; c++) descS[lane * 40 + c] = 0;  // K-pad
    }

    // ---- ph1: 3-body descriptors, full row per lane (no reduction) ----
    if (lane < K) {
        const int k = lane;
        const f4 uk = *(const f4*)&su[4 * k];
        f2 partv[6];
#pragma unroll
        for (int i = 0; i < 6; i++) partv[i] = (f2){0.0f, 0.0f};
#pragma unroll 1
        for (int l = 0; l < K; l++) {
            const f4 ul = *(const f4*)&su[4 * l];
            float c = uk.x * ul.x + uk.y * ul.y + uk.z * ul.z;
            if (k == l) c = 0.0f;
            const float cp1 = c + 1.0f;
            const float e0 = __builtin_amdgcn_exp2f(N4L * cp1 * cp1) * sfk[l];
            const float e1 = __builtin_amdgcn_exp2f(E1L * cp1);
            const float e2s = e1 * e1;
            const f2 e2v = {e2s, e2s};
            f2 tm = {e0, e0 * e1};
            partv[0] += tm;
#pragma unroll
            for (int i = 1; i < 6; i++) { tm *= e2v; partv[i] += tm; }
        }
#pragma unroll
        for (int i = 0; i < 6; i++) {
            const int m0 = 2 * i, m1 = 2 * i + 1;
            descS[k * 40 + NR + m0] = (short)f2bs(partv[i].x * __expf(CMC * (float)(m0 * m0)));
            descS[k * 40 + NR + m1] = (short)f2bs(partv[i].y * __expf(CMC * (float)(m1 * m1)));
        }
    }

    // ---- fwd1: h1 = tanh(desc @ W1 + b1), 48 rows x 64 cols, 12 MFMA ----
    {
        frag_ab wf1[4];
#pragma unroll
        for (int nt = 0; nt < 4; nt++)
            wf1[nt] = *(const frag_ab*)&g_w1t[(nt * 16 + lm) * 32 + quad * 8];
#pragma unroll 1
        for (int mt = 0; mt < 3; mt++) {
            const frag_ab a = *(const frag_ab*)&descS[(mt * 16 + lm) * 40 + quad * 8];
#pragma unroll
            for (int nt = 0; nt < 4; nt++) {
                frag_cd acc = {b1v[nt], b1v[nt], b1v[nt], b1v[nt]};
                acc = __builtin_amdgcn_mfma_f32_16x16x32_bf16(a, wf1[nt], acc, 0, 0, 0);
#pragma unroll
                for (int r = 0; r < 4; r++)
                    h1S[(mt * 16 + quad * 4 + r) * 72 + nt * 16 + lm] =
                        (short)f2bs(fast_tanh(acc[r]));
            }
        }
    }

    // ---- fwd2: t2 = tanh(h1@W2+b2); eij row-sums -> sgd[..17]; gz2 ----
    {
        frag_ab wa[4], wb[4];
#pragma unroll
        for (int nt = 0; nt < 4; nt++) {
            wa[nt] = *(const frag_ab*)&g_w2t[(nt * 16 + lm) * 64 + quad * 8];
            wb[nt] = *(const frag_ab*)&g_w2t[(nt * 16 + lm) * 64 + 32 + quad * 8];
        }
#pragma unroll 1
        for (int mt = 0; mt < 3; mt++) {
            const frag_ab a0 = *(const frag_ab*)&h1S[(mt * 16 + lm) * 72 + quad * 8];
            const frag_ab a1 = *(const frag_ab*)&h1S[(mt * 16 + lm) * 72 + 32 + quad * 8];
            const f4 fcv = *(const f4*)&sfc[mt * 16 + quad * 4];
            float ep[4] = {0.0f, 0.0f, 0.0f, 0.0f};
#pragma unroll
            for (int nt = 0; nt < 4; nt++) {
                frag_cd acc = {b2v[nt], b2v[nt], b2v[nt], b2v[nt]};
                acc = __builtin_amdgcn_mfma_f32_16x16x32_bf16(a0, wa[nt], acc, 0, 0, 0);
                acc = __builtin_amdgcn_mfma_f32_16x16x32_bf16(a1, wb[nt], acc, 0, 0, 0);
#pragma unroll
                for (int r = 0; r < 4; r++) {
                    const int row = mt * 16 + quad * 4 + r;
                    const float tv = fast_tanh(acc[r]);
                    ep[r] = fmaf(tv, w3v[nt], ep[r]);
                    gz2S[row * 72 + nt * 16 + lm] =
                        (short)f2bs(fcv[r] * w3v[nt] * (1.0f - tv * tv));
                }
            }
#pragma unroll
            for (int r = 0; r < 4; r++)
                ep[r] = dpp_add<0x118>(dpp_add<0x114>(dpp_add<0x112>(dpp_add<0x111>(ep[r]))));
            if (lm == 15) {
#pragma unroll
                for (int r = 0; r < 4; r++)
                    sgd[(mt * 16 + quad * 4 + r) * 20 + 17] = ep[r] + b3v;
            }
        }
    }

    // ---- bwd1: gz1 = (gz2 @ W2^T)*(1-t1^2) -> overwrite h1S ----
    {
        frag_ab wa[4], wb[4];
#pragma unroll
        for (int nt = 0; nt < 4; nt++) {
            wa[nt] = *(const frag_ab*)&g_w2r[(nt * 16 + lm) * 64 + quad * 8];
            wb[nt] = *(const frag_ab*)&g_w2r[(nt * 16 + lm) * 64 + 32 + quad * 8];
        }
#pragma unroll 1
        for (int mt = 0; mt < 3; mt++) {
            const frag_ab a0 = *(const frag_ab*)&gz2S[(mt * 16 + lm) * 72 + quad * 8];
            const frag_ab a1 = *(const frag_ab*)&gz2S[(mt * 16 + lm) * 72 + 32 + quad * 8];
#pragma unroll
            for (int nt = 0; nt < 4; nt++) {
                frag_cd acc = {0.0f, 0.0f, 0.0f, 0.0f};
                acc = __builtin_amdgcn_mfma_f32_16x16x32_bf16(a0, wa[nt], acc, 0, 0, 0);
                acc = __builtin_amdgcn_mfma_f32_16x16x32_bf16(a1, wb[nt], acc, 0, 0, 0);
#pragma unroll
                for (int r = 0; r < 4; r++) {
                    const int idx = (mt * 16 + quad * 4 + r) * 72 + nt * 16 + lm;
                    const float tv = bs2f((unsigned short)h1S[idx]);
                    h1S[idx] = (short)f2bs(acc[r] * (1.0f - tv * tv));
                }
            }
        }
    }

    // ---- bwd2: gdesc = gz1 @ W1^T -> sgd cols 0..16 (C_m pre-scaled) ----
    {
        frag_ab wa[2], wb[2];
#pragma unroll
        for (int nt = 0; nt < 2; nt++) {
            wa[nt] = *(const frag_ab*)&g_w1r[(nt * 16 + lm) * 64 + quad * 8];
            wb[nt] = *(const frag_ab*)&g_w1r[(nt * 16 + lm) * 64 + 32 + quad * 8];
        }
        const float cm0 = (lm >= NR)
            ? __expf(CMC * (float)((lm - NR) * (lm - NR))) : 1.0f;   // nt=0, n=lm
        const float cm1 = __expf(-16.0f);                            // n=16 -> m=11
#pragma unroll 1
        for (int mt = 0; mt < 3; mt++) {
            const frag_ab a0 = *(const frag_ab*)&h1S[(mt * 16 + lm) * 72 + quad * 8];
            const frag_ab a1 = *(const frag_ab*)&h1S[(mt * 16 + lm) * 72 + 32 + quad * 8];
            {
                frag_cd acc = {0.0f, 0.0f, 0.0f, 0.0f};
                acc = __builtin_amdgcn_mfma_f32_16x16x32_bf16(a0, wa[0], acc, 0, 0, 0);
                acc = __builtin_amdgcn_mfma_f32_16x16x32_bf16(a1, wb[0], acc, 0, 0, 0);
#pragma unroll
                for (int r = 0; r < 4; r++)
                    sgd[(mt * 16 + quad * 4 + r) * 20 + lm] = acc[r] * cm0;
            }
            {
                frag_cd acc = {0.0f, 0.0f, 0.0f, 0.0f};
                acc = __builtin_amdgcn_mfma_f32_16x16x32_bf16(a0, wa[1], acc, 0, 0, 0);
                acc = __builtin_amdgcn_mfma_f32_16x16x32_bf16(a1, wb[1], acc, 0, 0, 0);
                if (lm == 0) {
#pragma unroll
                    for (int r = 0; r < 4; r++)
                        sgd[(mt * 16 + quad * 4 + r) * 20 + 16] = acc[r] * cm1;
                }
            }
        }
    }

    // ---- 8b: recompute cos; dual Horner; S^T,T^T -> LDS; term1 in-reg ----
    float gx1 = 0.0f, gy1 = 0.0f, gz1 = 0.0f;
    if (lane < K) {
        const int k = lane;
        f2 gm[NM];
#pragma unroll
        for (int m = 0; m < NM; m++) {
            const float g = sgd[k * 20 + NR + m];
            gm[m] = (f2){g, (float)m * g};
        }
        const f4 uk = *(const f4*)&su[4 * k];
#pragma unroll 1
        for (int l = 0; l < K; l++) {
            const f4 ul = *(const f4*)&su[4 * l];
            float c = uk.x * ul.x + uk.y * ul.y + uk.z * ul.z;
            if (k == l) c = 0.0f;
            const float cp1 = c + 1.0f;
            const float e0 = __builtin_amdgcn_exp2f(N4L * cp1 * cp1);
            const float x = __builtin_amdgcn_exp2f(E1L * cp1);
            const f2 xx = {x, x};
            f2 pd = gm[11];
#pragma unroll
            for (int m = 10; m >= 1; m--) pd = __builtin_elementwise_fma(pd, xx, gm[m]);
            const float Pv = fmaf(pd.x, x, gm[0].x);
            const float T = e0 * Pv;
            const float U = e0 * x * pd.y;
            const float Sp = fmaf(cp1, T, -(2.0f / 11.0f) * U);
            const float Sv = (k == l) ? 0.0f : (-8.0f) * Sp;
            tT[l * 52 + k] = f2bs(T);        // transposed stores
            tS[l * 52 + k] = f2bs(Sv);
            const float A = Sv * sfk[l];
            gx1 = fmaf(A, ul.x, gx1);
            gy1 = fmaf(A, ul.y, gy1);
            gz1 = fmaf(A, ul.z, gz1);
        }
    }

    // ---- 8c+8d: contiguous row reads of T^T/S^T; assemble; write out ----
    if (lane < K) {
        const int k = lane;
        float sgf_t = 0.0f, gx2 = 0.0f, gy2 = 0.0f, gz2v = 0.0f;
#pragma unroll 1
        for (int i = 0; i < 12; i++) {
            const s4 tv4 = *(const s4*)&tT[k * 52 + 4 * i];
            const s4 sv4 = *(const s4*)&tS[k * 52 + 4 * i];
#pragma unroll
            for (int j = 0; j < 4; j++) {
                const int l = 4 * i + j;
                const f4 ul = *(const f4*)&su[4 * l];
                sgf_t += bs2f((unsigned short)tv4[j]);
                const float Sv = bs2f((unsigned short)sv4[j]);
                gx2 = fmaf(Sv, ul.x, gx2);
                gy2 = fmaf(Sv, ul.y, gy2);
                gz2v = fmaf(Sv, ul.z, gz2v);
            }
        }
        const float fk = sfk[k];
        const float gux = gx1 + fk * gx2;
        const float guy = gy1 + fk * gy2;
        const float guz = gz1 + fk * gz2v;

        const f4 uv = *(const f4*)&su[4 * k];
        const float d = uv.w;
        const float ux = uv.x, uy = uv.y, uz = uv.z;
        const float invd = __builtin_amdgcn_rcpf(d);
        float gfc = sgd[k * 20 + 17];
        float gdR = 0.0f;
        float s1, c1;
        __sincosf(POC * d, &s1, &c1);
        float sn = s1, cn = c1, bn = POC;
#pragma unroll 1
        for (int n = 0; n < NR; n++) {
            const float g = sgd[k * 20 + n];
            gfc = fmaf(g, SQ * sn * invd, gfc);
            gdR = fmaf(g, SQ * (bn * cn - sn * invd) * invd, gdR);
            const float snx = sn * c1 + cn * s1;
            cn = cn * c1 - sn * s1;
            sn = snx;
            bn += POC;
        }
        const float fc = sfc[k];
        float dfc = 0.0f;
        if (d > RMIN_F) dfc = -0.5f * AFC * __sinf(AFC * (d - RMIN_F));
        const float dfcrik = -0.5f * POC * __sinf(POC * d);

        const float gd = fc * gdR + gfc * dfc + sgf_t * dfcrik;
        const float dot = gux * ux + guy * uy + guz * uz;

        out[base3 + 3 * k + 0] = fmaf(gd, ux, (gux - dot * ux) * invd);
        out[base3 + 3 * k + 1] = fmaf(gd, uy, (guy - dot * uy) * invd);
        out[base3 + 3 * k + 2] = fmaf(gd, uz, (guz - dot * uz) * invd);
    }
}

extern "C" void kernel_launch(void* const* d_in, const int* in_sizes, int n_in,
                              void* d_out, int out_size, void* d_ws, size_t ws_size,
                              hipStream_t stream) {
    (void)in_sizes; (void)n_in; (void)out_size; (void)d_ws; (void)ws_size;
    const float* rij = (const float*)d_in[0];
    // d_in[1] = unique_i (unused: dense K neighbors per atom)
    const float* W1 = (const float*)d_in[2];
    const float* b1 = (const float*)d_in[3];
    const float* W2 = (const float*)d_in[4];
    const float* b2 = (const float*)d_in[5];
    const float* W3 = (const float*)d_in[6];
    const float* b3 = (const float*)d_in[7];
    float* out = (float*)d_out;

    k_prep<<<48, 256, 0, stream>>>(W1, W2);
    k_fused<<<NATOMS, 64, 0, stream>>>(rij, b1, b2, W3, b3, out);
}